// Round 1
// baseline (805.208 us; speedup 1.0000x reference)
//
#include <hip/hip_runtime.h>
#include <hip/hip_bf16.h>
#include <cmath>

#define B_ 8
#define W_LEN_ 1000
#define V_ 50000
#define E_ 100
#define C_ 50
#define K_ 3
#define L_ 18000

#define WT 128          // w-tile staged in LDS for attention kernel
#define TLB 256         // labels per block (== blockDim.x)

// ---------------- Kernel A: embedding gather + conv1d(K=3,'same') + tanh ----------------
// One thread per (b, w, c). Output H laid out (B, W, C) so attention reads are contiguous.
__global__ __launch_bounds__(256) void conv_kernel(
    const int* __restrict__ x,          // (B, W)
    const float* __restrict__ W_embed,  // (V, E)
    const float* __restrict__ conv_w,   // (C, E, K)
    const float* __restrict__ conv_b,   // (C,)
    float* __restrict__ H)              // (B, W, C)
{
    int tid = blockIdx.x * blockDim.x + threadIdx.x;
    const int total = B_ * W_LEN_ * C_;
    if (tid >= total) return;
    int c = tid % C_;
    int w = (tid / C_) % W_LEN_;
    int b = tid / (C_ * W_LEN_);

    float acc = conv_b[c];
    #pragma unroll
    for (int k = 0; k < K_; k++) {
        int ws = w + k - 1;                 // K//2 = 1 left pad
        if ((unsigned)ws < (unsigned)W_LEN_) {
            const float* erow = W_embed + (size_t)x[b * W_LEN_ + ws] * E_;
            const float* kw   = conv_w + (size_t)c * E_ * K_ + k;   // stride K_ over e
            float a0 = 0.f, a1 = 0.f;
            #pragma unroll 2
            for (int e = 0; e < E_; e += 2) {
                a0 += erow[e]     * kw[e * K_];
                a1 += erow[e + 1] * kw[(e + 1) * K_];
            }
            acc += a0 + a1;
        }
    }
    H[tid] = tanhf(acc);
}

// ---------------- Kernel B: fused label-attention ----------------
// Grid: (ceil(L/TLB), B). One thread owns one label end-to-end.
// Single pass: no max-subtraction needed (|score| <= ~4 with these scales),
// softmax(s) = exp(s)/sum exp(s) exactly matches reference math.
__global__ __launch_bounds__(TLB) void attn_kernel(
    const float* __restrict__ H,      // (B, W, C)
    const float* __restrict__ u_w,    // (L, C)
    const float* __restrict__ out_w,  // (L, C)
    const float* __restrict__ out_b,  // (L,)
    float* __restrict__ out)          // (B, L)
{
    __shared__ float Hs[WT * C_];     // 25.6 KB

    const int b = blockIdx.y;
    const int l = blockIdx.x * TLB + threadIdx.x;
    const bool valid = (l < L_);

    float u[C_];
    #pragma unroll
    for (int c = 0; c < C_; c++) u[c] = valid ? u_w[(size_t)l * C_ + c] : 0.f;

    float macc[C_];
    #pragma unroll
    for (int c = 0; c < C_; c++) macc[c] = 0.f;
    float lsum = 0.f;

    const float* Hb = H + (size_t)b * W_LEN_ * C_;

    for (int wt = 0; wt < W_LEN_; wt += WT) {
        const int wn = min(WT, W_LEN_ - wt);
        const int nv4 = (wn * C_) / 4;            // always divisible (128*50, 104*50)
        __syncthreads();                          // previous tile fully consumed
        const float4* src = (const float4*)(Hb + (size_t)wt * C_);
        float4* dst = (float4*)Hs;
        for (int i = threadIdx.x; i < nv4; i += TLB) dst[i] = src[i];
        __syncthreads();

        for (int w = 0; w < wn; w++) {
            const float* h = &Hs[w * C_];
            // pull tile row into registers once; broadcast LDS reads (conflict-free)
            float hv[C_];
            #pragma unroll
            for (int c = 0; c < C_; c++) hv[c] = h[c];
            // dot(u, h) with 4 partial accumulators to break the dep chain
            float s0 = 0.f, s1 = 0.f, s2 = 0.f, s3 = 0.f;
            #pragma unroll
            for (int c = 0; c < C_ - 2; c += 4) {
                s0 += u[c]     * hv[c];
                s1 += u[c + 1] * hv[c + 1];
                s2 += u[c + 2] * hv[c + 2];
                s3 += u[c + 3] * hv[c + 3];
            }
            s0 += u[C_ - 2] * hv[C_ - 2];
            s1 += u[C_ - 1] * hv[C_ - 1];
            float p = __expf((s0 + s2) + (s1 + s3));
            lsum += p;
            #pragma unroll
            for (int c = 0; c < C_; c++) macc[c] += p * hv[c];
        }
    }

    if (valid) {
        float o0 = 0.f, o1 = 0.f;
        #pragma unroll
        for (int c = 0; c < C_; c += 2) {
            o0 += out_w[(size_t)l * C_ + c]     * macc[c];
            o1 += out_w[(size_t)l * C_ + c + 1] * macc[c + 1];
        }
        float z = (o0 + o1) / lsum + out_b[l];
        out[(size_t)b * L_ + l] = 1.f / (1.f + __expf(-z));
    }
}

extern "C" void kernel_launch(void* const* d_in, const int* in_sizes, int n_in,
                              void* d_out, int out_size, void* d_ws, size_t ws_size,
                              hipStream_t stream) {
    const int*   x       = (const int*)  d_in[0];
    const float* W_embed = (const float*)d_in[1];
    const float* conv_w  = (const float*)d_in[2];
    const float* conv_b  = (const float*)d_in[3];
    const float* u_w     = (const float*)d_in[4];
    const float* out_w   = (const float*)d_in[5];
    const float* out_b   = (const float*)d_in[6];
    float* out = (float*)d_out;
    float* H   = (float*)d_ws;   // (B, W, C) fp32 = 1.6 MB

    {
        const int total = B_ * W_LEN_ * C_;
        dim3 grid((total + 255) / 256);
        conv_kernel<<<grid, 256, 0, stream>>>(x, W_embed, conv_w, conv_b, H);
    }
    {
        dim3 grid((L_ + TLB - 1) / TLB, B_);
        attn_kernel<<<grid, TLB, 0, stream>>>(H, u_w, out_w, out_b, out);
    }
}

// Round 2
// 533.446 us; speedup vs baseline: 1.5094x; 1.5094x over previous
//
#include <hip/hip_runtime.h>
#include <hip/hip_bf16.h>
#include <cmath>

#define B_ 8
#define W_LEN_ 1000
#define V_ 50000
#define E_ 100
#define C_ 50
#define K_ 3
#define L_ 18000

#define CP 52           // padded channel stride (208 B = 13 float4, 16B-aligned)
#define NCH 4           // W split into NCH chunks (250 w each)
#define WCH (W_LEN_ / NCH)
#define WT 125          // w-tile staged in LDS (2 tiles per chunk)
#define TLB 256         // labels per block

// ---------------- Kernel T: transpose conv_w (C,E,K) -> (C,K,E) ----------------
__global__ __launch_bounds__(256) void transpose_kernel(
    const float* __restrict__ conv_w, float* __restrict__ cwT)
{
    int idx = blockIdx.x * blockDim.x + threadIdx.x;
    if (idx >= C_ * K_ * E_) return;
    int c = idx / (K_ * E_);
    int r = idx % (K_ * E_);
    int k = r / E_;
    int e = r % E_;
    cwT[idx] = conv_w[(size_t)c * E_ * K_ + e * K_ + k];
}

// ---------------- Kernel A: embedding gather + conv1d + tanh -> padded H ----------------
// One thread per (b, w, cp) with cp in [0,52); cp>=50 writes the zero pad.
__global__ __launch_bounds__(256) void conv_kernel(
    const int* __restrict__ x,          // (B, W)
    const float* __restrict__ W_embed,  // (V, E), rows 400B-aligned
    const float* __restrict__ cwT,      // (C, K, E)
    const float* __restrict__ conv_b,   // (C,)
    float* __restrict__ H)              // (B, W, CP)
{
    int tid = blockIdx.x * blockDim.x + threadIdx.x;
    const int total = B_ * W_LEN_ * CP;
    if (tid >= total) return;
    int c = tid % CP;
    int w = (tid / CP) % W_LEN_;
    int b = tid / (CP * W_LEN_);

    if (c >= C_) { H[tid] = 0.f; return; }

    float4 a4 = make_float4(conv_b[c], 0.f, 0.f, 0.f);
    #pragma unroll
    for (int k = 0; k < K_; k++) {
        int ws = w + k - 1;
        if ((unsigned)ws < (unsigned)W_LEN_) {
            const float4* e4 = (const float4*)(W_embed + (size_t)x[b * W_LEN_ + ws] * E_);
            const float4* w4 = (const float4*)(cwT + ((size_t)c * K_ + k) * E_);
            #pragma unroll
            for (int i = 0; i < E_ / 4; i++) {
                float4 ev = e4[i], wv = w4[i];
                a4.x += ev.x * wv.x;
                a4.y += ev.y * wv.y;
                a4.z += ev.z * wv.z;
                a4.w += ev.w * wv.w;
            }
        }
    }
    H[tid] = tanhf((a4.x + a4.z) + (a4.y + a4.w));
}

// ---------------- Kernel B: fused label-attention, W-chunked ----------------
// Grid: (ceil(L/TLB), B, NCH). Thread owns one label; emits (numer, lsum) partial.
// numer = sum_w exp(s_w) * dot(out_w_l, h_w);  lsum = sum_w exp(s_w).
__global__ __launch_bounds__(TLB) void attn_kernel(
    const float* __restrict__ H,      // (B, W, CP)
    const float* __restrict__ u_w,    // (L, C)
    const float* __restrict__ out_w,  // (L, C)
    float2* __restrict__ part)        // (NCH, B, L)
{
    __shared__ float Hs[WT * CP];     // 26 KB

    const int b = blockIdx.y;
    const int chunk = blockIdx.z;
    const int l = blockIdx.x * TLB + threadIdx.x;
    const bool valid = (l < L_);

    float u[CP], ow[CP];
    #pragma unroll
    for (int c = 0; c < C_; c++) {
        u[c]  = valid ? u_w[(size_t)l * C_ + c]   : 0.f;
        ow[c] = valid ? out_w[(size_t)l * C_ + c] : 0.f;
    }
    #pragma unroll
    for (int c = C_; c < CP; c++) { u[c] = 0.f; ow[c] = 0.f; }

    float lsum = 0.f, num = 0.f;
    const int w0 = chunk * WCH;

    for (int wt = w0; wt < w0 + WCH; wt += WT) {
        __syncthreads();
        const float4* src = (const float4*)(H + ((size_t)b * W_LEN_ + wt) * CP);
        float4* dst = (float4*)Hs;
        for (int i = threadIdx.x; i < WT * CP / 4; i += TLB) dst[i] = src[i];
        __syncthreads();

        for (int w = 0; w < WT; w++) {
            const float4* h4 = (const float4*)(Hs + w * CP);  // 208B rows, 16B-aligned
            float s0 = 0.f, s1 = 0.f, s2 = 0.f, s3 = 0.f;
            float t0 = 0.f, t1 = 0.f, t2 = 0.f, t3 = 0.f;
            #pragma unroll
            for (int c4 = 0; c4 < CP / 4; c4++) {
                float4 hc = h4[c4];           // ds_read_b128, broadcast
                int c = c4 * 4;
                s0 += u[c]     * hc.x;  t0 += ow[c]     * hc.x;
                s1 += u[c + 1] * hc.y;  t1 += ow[c + 1] * hc.y;
                s2 += u[c + 2] * hc.z;  t2 += ow[c + 2] * hc.z;
                s3 += u[c + 3] * hc.w;  t3 += ow[c + 3] * hc.w;
            }
            float p = __expf((s0 + s2) + (s1 + s3));
            lsum += p;
            num  += p * ((t0 + t2) + (t1 + t3));
        }
    }

    if (valid) part[((size_t)chunk * B_ + b) * L_ + l] = make_float2(num, lsum);
}

// ---------------- Kernel R: reduce chunks + sigmoid ----------------
__global__ __launch_bounds__(256) void reduce_kernel(
    const float2* __restrict__ part,  // (NCH, B, L)
    const float* __restrict__ out_b,  // (L,)
    float* __restrict__ out)          // (B, L)
{
    int tid = blockIdx.x * blockDim.x + threadIdx.x;
    if (tid >= B_ * L_) return;
    int b = tid / L_;
    int l = tid % L_;
    float num = 0.f, ls = 0.f;
    #pragma unroll
    for (int ch = 0; ch < NCH; ch++) {
        float2 p = part[((size_t)ch * B_ + b) * L_ + l];
        num += p.x;
        ls  += p.y;
    }
    float z = num / ls + out_b[l];
    out[tid] = 1.f / (1.f + __expf(-z));
}

extern "C" void kernel_launch(void* const* d_in, const int* in_sizes, int n_in,
                              void* d_out, int out_size, void* d_ws, size_t ws_size,
                              hipStream_t stream) {
    const int*   x       = (const int*)  d_in[0];
    const float* W_embed = (const float*)d_in[1];
    const float* conv_w  = (const float*)d_in[2];
    const float* conv_b  = (const float*)d_in[3];
    const float* u_w     = (const float*)d_in[4];
    const float* out_w   = (const float*)d_in[5];
    const float* out_b   = (const float*)d_in[6];
    float* out = (float*)d_out;

    float*  H    = (float*)d_ws;                        // B*W*CP floats (1.664 MB)
    float*  cwT  = H + (size_t)B_ * W_LEN_ * CP;        // C*K*E floats (60 KB)
    float2* part = (float2*)(cwT + C_ * K_ * E_);       // NCH*B*L float2 (4.6 MB)

    {
        const int total = C_ * K_ * E_;
        transpose_kernel<<<dim3((total + 255) / 256), 256, 0, stream>>>(conv_w, cwT);
    }
    {
        const int total = B_ * W_LEN_ * CP;
        conv_kernel<<<dim3((total + 255) / 256), 256, 0, stream>>>(x, W_embed, cwT, conv_b, H);
    }
    {
        dim3 grid((L_ + TLB - 1) / TLB, B_, NCH);
        attn_kernel<<<grid, TLB, 0, stream>>>(H, u_w, out_w, part);
    }
    {
        const int total = B_ * L_;
        reduce_kernel<<<dim3((total + 255) / 256), 256, 0, stream>>>(part, out_b, out);
    }
}

// Round 3
// 268.681 us; speedup vs baseline: 2.9969x; 1.9854x over previous
//
#include <hip/hip_runtime.h>
#include <hip/hip_bf16.h>
#include <cmath>

#define B_ 8
#define W_LEN_ 1000
#define WP 1024          // W padded (rows >= 1000 zeroed, masked in attn)
#define V_ 50000
#define E_ 100
#define C_ 50
#define CPAD 64          // channel dim padded for K=64 (2 x K=32 MFMA steps)
#define K_ 3
#define L_ 18000
#define TL 64            // labels per attn block
#define NLBLK ((L_ + TL - 1) / TL)   // 282

typedef __attribute__((ext_vector_type(8))) short bf16x8;   // 8 bf16 = 4 VGPRs
typedef __attribute__((ext_vector_type(4))) float f32x4;

// ---------------- transpose conv_w (C,E,K) -> (C,K,E) ----------------
__global__ __launch_bounds__(256) void transpose_kernel(
    const float* __restrict__ conv_w, float* __restrict__ cwT)
{
    int idx = blockIdx.x * blockDim.x + threadIdx.x;
    if (idx >= C_ * K_ * E_) return;
    int c = idx / (K_ * E_);
    int r = idx % (K_ * E_);
    int k = r / E_;
    int e = r % E_;
    cwT[idx] = conv_w[(size_t)c * E_ * K_ + e * K_ + k];
}

// ---------------- prep: u_w/out_w fp32 (L,50) -> bf16 (2,L,64) zero-padded ----------------
__global__ __launch_bounds__(256) void prep_uo(
    const float* __restrict__ u_w, const float* __restrict__ out_w,
    __hip_bfloat16* __restrict__ UO)
{
    int tid = blockIdx.x * blockDim.x + threadIdx.x;
    if (tid >= 2 * L_ * CPAD) return;
    int c = tid & (CPAD - 1);
    int l = (tid >> 6) % L_;
    int m = tid / (L_ * CPAD);
    const float* src = m ? out_w : u_w;
    float v = (c < C_) ? src[(size_t)l * C_ + c] : 0.f;
    UO[tid] = __float2bfloat16(v);
}

// ---------------- conv: embed gather + conv1d + tanh -> bf16 H (B,1024,64) ----------------
__global__ __launch_bounds__(256) void conv_kernel(
    const int* __restrict__ x,          // (B, W)
    const float* __restrict__ W_embed,  // (V, E)
    const float* __restrict__ cwT,      // (C, K, E)
    const float* __restrict__ conv_b,   // (C,)
    __hip_bfloat16* __restrict__ H)     // (B, WP, CPAD)
{
    int tid = blockIdx.x * blockDim.x + threadIdx.x;
    const int total = B_ * WP * CPAD;   // 2^19
    if (tid >= total) return;
    int c = tid & (CPAD - 1);
    int w = (tid >> 6) & (WP - 1);
    int b = tid >> 16;

    if (c >= C_ || w >= W_LEN_) { H[tid] = __float2bfloat16(0.f); return; }

    float4 a4 = make_float4(conv_b[c], 0.f, 0.f, 0.f);
    #pragma unroll
    for (int k = 0; k < K_; k++) {
        int ws = w + k - 1;
        if ((unsigned)ws < (unsigned)W_LEN_) {
            const float4* e4 = (const float4*)(W_embed + (size_t)x[b * W_LEN_ + ws] * E_);
            const float4* w4 = (const float4*)(cwT + ((size_t)c * K_ + k) * E_);
            #pragma unroll
            for (int i = 0; i < E_ / 4; i++) {
                float4 ev = e4[i], wv = w4[i];
                a4.x += ev.x * wv.x;
                a4.y += ev.y * wv.y;
                a4.z += ev.z * wv.z;
                a4.w += ev.w * wv.w;
            }
        }
    }
    H[tid] = __float2bfloat16(tanhf((a4.x + a4.z) + (a4.y + a4.w)));
}

// ---------------- attn: MFMA dual-GEMM (S=U.H^T, T=O.H^T) + fused softmax-pool ----------------
// Grid (NLBLK, B). 4 waves: (mi,ni) = 2 label-halves x 2 w-halves; wave tile 32 lbl x 32 w.
// 16x16x32 bf16 MFMA. A[m=lane&15][k=(lane>>4)*8+j]; B[k][n=lane&15] same k-map;
// D: col=lane&15 (w), row=(lane>>4)*4+reg (label).
__global__ __launch_bounds__(256) void attn_kernel(
    const __hip_bfloat16* __restrict__ H,   // (B, WP, CPAD)
    const __hip_bfloat16* __restrict__ UO,  // (2, L, CPAD)
    const float* __restrict__ out_b,        // (L,)
    float* __restrict__ out)                // (B, L)
{
    __shared__ float2 red[2][TL];   // [ni][label_local] -> (lsum, num)

    const int b  = blockIdx.y;
    const int l0 = blockIdx.x * TL;
    const int tid  = threadIdx.x;
    const int lane = tid & 63;
    const int wid  = tid >> 6;
    const int mi = wid & 1, ni = wid >> 1;
    const int col = lane & 15, quad = lane >> 4;

    // loop-invariant A-fragments for U and O (2 m-tiles x 2 K-steps each)
    bf16x8 Uf[2][2], Of[2][2];
    #pragma unroll
    for (int mt = 0; mt < 2; mt++) {
        int l = l0 + mi * 32 + mt * 16 + col;
        if (l >= L_) l = L_ - 1;                       // clamp; result discarded
        const __hip_bfloat16* up = UO + (size_t)l * CPAD + quad * 8;
        const __hip_bfloat16* op = up + (size_t)L_ * CPAD;
        #pragma unroll
        for (int st = 0; st < 2; st++) {
            Uf[mt][st] = *(const bf16x8*)(up + st * 32);
            Of[mt][st] = *(const bf16x8*)(op + st * 32);
        }
    }

    f32x4 lsum[2] = {{0.f,0.f,0.f,0.f},{0.f,0.f,0.f,0.f}};
    f32x4 num [2] = {{0.f,0.f,0.f,0.f},{0.f,0.f,0.f,0.f}};
    const f32x4 zero = {0.f, 0.f, 0.f, 0.f};

    const __hip_bfloat16* Hb = H + (size_t)b * WP * CPAD;

    for (int wt = 0; wt < WP; wt += 64) {
        const int wbase = wt + ni * 32;
        // B-fragments: lane reads H[w = wbase + nt*16 + col][c = quad*8 + st*32 ..+7]
        bf16x8 Bf[2][2];
        #pragma unroll
        for (int nt = 0; nt < 2; nt++)
            #pragma unroll
            for (int st = 0; st < 2; st++)
                Bf[nt][st] = *(const bf16x8*)(Hb + (size_t)(wbase + nt * 16 + col) * CPAD
                                              + quad * 8 + st * 32);

        #pragma unroll
        for (int nt = 0; nt < 2; nt++) {
            const float msk = (wbase + nt * 16 + col < W_LEN_) ? 1.f : 0.f;
            #pragma unroll
            for (int mt = 0; mt < 2; mt++) {
                f32x4 S = __builtin_amdgcn_mfma_f32_16x16x32_bf16(Uf[mt][0], Bf[nt][0], zero, 0, 0, 0);
                S       = __builtin_amdgcn_mfma_f32_16x16x32_bf16(Uf[mt][1], Bf[nt][1], S,    0, 0, 0);
                f32x4 T = __builtin_amdgcn_mfma_f32_16x16x32_bf16(Of[mt][0], Bf[nt][0], zero, 0, 0, 0);
                T       = __builtin_amdgcn_mfma_f32_16x16x32_bf16(Of[mt][1], Bf[nt][1], T,    0, 0, 0);
                #pragma unroll
                for (int r = 0; r < 4; r++) {
                    float p = __expf(S[r]) * msk;   // |s|<=~4: no max-subtraction needed
                    lsum[mt][r] += p;
                    num [mt][r] += p * T[r];
                }
            }
        }
    }

    // reduce over the 16 cols held by lanes sharing (quad): xor-butterfly on lane bits 0-3
    #pragma unroll
    for (int mt = 0; mt < 2; mt++) {
        #pragma unroll
        for (int r = 0; r < 4; r++) {
            float ls = lsum[mt][r], nm = num[mt][r];
            #pragma unroll
            for (int d = 1; d < 16; d <<= 1) {
                ls += __shfl_xor(ls, d, 64);
                nm += __shfl_xor(nm, d, 64);
            }
            if (col == 0)
                red[ni][mi * 32 + mt * 16 + quad * 4 + r] = make_float2(ls, nm);
        }
    }
    __syncthreads();

    if (tid < TL) {
        int l = l0 + tid;
        if (l < L_) {
            float2 p0 = red[0][tid], p1 = red[1][tid];
            float z = (p0.y + p1.y) / (p0.x + p1.x) + out_b[l];
            out[(size_t)b * L_ + l] = 1.f / (1.f + __expf(-z));
        }
    }
}

extern "C" void kernel_launch(void* const* d_in, const int* in_sizes, int n_in,
                              void* d_out, int out_size, void* d_ws, size_t ws_size,
                              hipStream_t stream) {
    const int*   x       = (const int*)  d_in[0];
    const float* W_embed = (const float*)d_in[1];
    const float* conv_w  = (const float*)d_in[2];
    const float* conv_b  = (const float*)d_in[3];
    const float* u_w     = (const float*)d_in[4];
    const float* out_w   = (const float*)d_in[5];
    const float* out_b   = (const float*)d_in[6];
    float* out = (float*)d_out;

    char* ws = (char*)d_ws;
    __hip_bfloat16* H  = (__hip_bfloat16*)ws;                       // 8*1024*64*2 = 1,048,576 B
    __hip_bfloat16* UO = (__hip_bfloat16*)(ws + 1048576);           // 2*18000*64*2 = 4,608,000 B
    float*          cwT = (float*)(ws + 1048576 + 4608000);         // 60,000 B

    {
        const int total = C_ * K_ * E_;
        transpose_kernel<<<dim3((total + 255) / 256), 256, 0, stream>>>(conv_w, cwT);
    }
    {
        const int total = 2 * L_ * CPAD;
        prep_uo<<<dim3((total + 255) / 256), 256, 0, stream>>>(u_w, out_w, UO);
    }
    {
        const int total = B_ * WP * CPAD;
        conv_kernel<<<dim3((total + 255) / 256), 256, 0, stream>>>(x, W_embed, cwT, conv_b, H);
    }
    {
        dim3 grid(NLBLK, B_);
        attn_kernel<<<grid, 256, 0, stream>>>(H, UO, out_b, out);
    }
}

// Round 4
// 178.434 us; speedup vs baseline: 4.5126x; 1.5058x over previous
//
#include <hip/hip_runtime.h>
#include <hip/hip_bf16.h>
#include <cmath>

#define B_ 8
#define W_LEN_ 1000
#define WP 1024          // W padded; rows >= 1000 are exactly 0 -> lsum pad = +24, subtracted at end
#define V_ 50000
#define E_ 100
#define C_ 50
#define CPAD 64          // channel dim padded for K=64 (2 x K=32 MFMA steps)
#define K_ 3
#define L_ 18000
#define TL 64            // labels per attn block
#define NLBLK ((L_ + TL - 1) / TL)   // 282
#define CWT 16           // w-positions per conv block

typedef __attribute__((ext_vector_type(8))) short bf16x8;   // 8 bf16 = 4 VGPRs
typedef __attribute__((ext_vector_type(4))) float f32x4;

// ---------------- transpose conv_w (C,E,K) -> (C,K,E) ----------------
__global__ __launch_bounds__(256) void transpose_kernel(
    const float* __restrict__ conv_w, float* __restrict__ cwT)
{
    int idx = blockIdx.x * blockDim.x + threadIdx.x;
    if (idx >= C_ * K_ * E_) return;
    int c = idx / (K_ * E_);
    int r = idx % (K_ * E_);
    int k = r / E_;
    int e = r % E_;
    cwT[idx] = conv_w[(size_t)c * E_ * K_ + e * K_ + k];
}

// ---------------- prep: u_w/out_w fp32 (L,50) -> bf16 (2,L,64) zero-padded ----------------
__global__ __launch_bounds__(256) void prep_uo(
    const float* __restrict__ u_w, const float* __restrict__ out_w,
    __hip_bfloat16* __restrict__ UO)
{
    int tid = blockIdx.x * blockDim.x + threadIdx.x;
    if (tid >= 2 * L_ * CPAD) return;
    int c = tid & (CPAD - 1);
    int l = (tid >> 6) % L_;
    int m = tid / (L_ * CPAD);
    const float* src = m ? out_w : u_w;
    float v = (c < C_) ? src[(size_t)l * C_ + c] : 0.f;
    UO[tid] = __float2bfloat16(v);
}

// ---------------- conv: LDS-staged embed rows, 4 w per thread ----------------
// Grid (WP/CWT, B). Block: 256 threads = (c 0..63) x (wq 0..3); thread computes
// w = w0 + wq*4 + j for j=0..3, reusing each weight float4 across the 4 w.
__global__ __launch_bounds__(256) void conv_kernel(
    const int* __restrict__ x,          // (B, W)
    const float* __restrict__ W_embed,  // (V, E)
    const float* __restrict__ cwT,      // (C, K, E)
    const float* __restrict__ conv_b,   // (C,)
    __hip_bfloat16* __restrict__ H)     // (B, WP, CPAD)
{
    __shared__ float4 emb_s[(CWT + 2) * (E_ / 4)];   // 18 rows x 25 float4 = 7.2 KB

    const int b  = blockIdx.y;
    const int w0 = blockIdx.x * CWT;
    const int tid = threadIdx.x;

    // stage rows ws = w0-1 .. w0+16 (zero-filled outside [0, W_LEN))
    for (int i = tid; i < (CWT + 2) * (E_ / 4); i += 256) {
        int row = i / (E_ / 4);
        int e4  = i % (E_ / 4);
        int ws  = w0 - 1 + row;
        float4 v = make_float4(0.f, 0.f, 0.f, 0.f);
        if ((unsigned)ws < (unsigned)W_LEN_)
            v = ((const float4*)(W_embed + (size_t)x[b * W_LEN_ + ws] * E_))[e4];
        emb_s[i] = v;
    }
    __syncthreads();

    const int c  = tid & 63;
    const int wq = tid >> 6;          // 0..3
    const int cc = (c < C_) ? c : 0;  // dead lanes compute c=0, write 0

    f32x4 acc[4];
    const float bias = conv_b[cc];
    #pragma unroll
    for (int j = 0; j < 4; j++) acc[j] = (f32x4){bias, 0.f, 0.f, 0.f};

    const float4* kw = (const float4*)(cwT + (size_t)cc * K_ * E_);  // k rows contiguous, 25 f4 each
    const float4* eb = &emb_s[wq * 4 * (E_ / 4)];                    // thread's 7-row window base

    #pragma unroll 5
    for (int i = 0; i < E_ / 4; i++) {
        float4 k0 = kw[i], k1 = kw[25 + i], k2 = kw[50 + i];
        float4 e0 = eb[i],            e1 = eb[25 + i],  e2 = eb[50 + i];
        float4 e3 = eb[75 + i],       e4 = eb[100 + i], e5 = eb[125 + i];
        // acc[j] += emb[row=j+k] * k_k  (row index in thread window = j + k)
        acc[0].x += e0.x*k0.x + e1.x*k1.x + e2.x*k2.x;
        acc[0].y += e0.y*k0.y + e1.y*k1.y + e2.y*k2.y;
        acc[0].z += e0.z*k0.z + e1.z*k1.z + e2.z*k2.z;
        acc[0].w += e0.w*k0.w + e1.w*k1.w + e2.w*k2.w;
        acc[1].x += e1.x*k0.x + e2.x*k1.x + e3.x*k2.x;
        acc[1].y += e1.y*k0.y + e2.y*k1.y + e3.y*k2.y;
        acc[1].z += e1.z*k0.z + e2.z*k1.z + e3.z*k2.z;
        acc[1].w += e1.w*k0.w + e2.w*k1.w + e3.w*k2.w;
        acc[2].x += e2.x*k0.x + e3.x*k1.x + e4.x*k2.x;
        acc[2].y += e2.y*k0.y + e3.y*k1.y + e4.y*k2.y;
        acc[2].z += e2.z*k0.z + e3.z*k1.z + e4.z*k2.z;
        acc[2].w += e2.w*k0.w + e3.w*k1.w + e4.w*k2.w;
        acc[3].x += e3.x*k0.x + e4.x*k1.x + e5.x*k2.x;
        acc[3].y += e3.y*k0.y + e4.y*k1.y + e5.y*k2.y;
        acc[3].z += e3.z*k0.z + e4.z*k1.z + e5.z*k2.z;
        acc[3].w += e3.w*k0.w + e4.w*k1.w + e5.w*k2.w;
    }

    #pragma unroll
    for (int j = 0; j < 4; j++) {
        int w = w0 + wq * 4 + j;
        float v = 0.f;
        if (c < C_ && w < W_LEN_)
            v = tanhf((acc[j].x + acc[j].z) + (acc[j].y + acc[j].w));
        H[((size_t)b * WP + w) * CPAD + c] = __float2bfloat16(v);
    }
}

// ---------------- attn: MFMA dual-GEMM (S=U.H^T, T=O.H^T) + fused softmax-pool ----------------
// Grid (NLBLK, B). 4 waves: (mi,ni) = 2 label-halves x 2 w-halves; wave tile 32 lbl x 32 w.
// Software-pipelined wt loop (unroll 1) -> no spills. Pad rows contribute exp(0)=1 to lsum
// and 0 to num; corrected by subtracting 24 at the end.
__global__ __launch_bounds__(256) void attn_kernel(
    const __hip_bfloat16* __restrict__ H,   // (B, WP, CPAD)
    const __hip_bfloat16* __restrict__ UO,  // (2, L, CPAD)
    const float* __restrict__ out_b,        // (L,)
    float* __restrict__ out)                // (B, L)
{
    __shared__ float2 red[2][TL];   // [ni][label_local] -> (lsum, num)

    const int b  = blockIdx.y;
    const int l0 = blockIdx.x * TL;
    const int tid  = threadIdx.x;
    const int lane = tid & 63;
    const int wid  = tid >> 6;
    const int mi = wid & 1, ni = wid >> 1;
    const int col = lane & 15, quad = lane >> 4;

    // loop-invariant A-fragments for U and O
    bf16x8 Uf[2][2], Of[2][2];
    #pragma unroll
    for (int mt = 0; mt < 2; mt++) {
        int l = l0 + mi * 32 + mt * 16 + col;
        if (l >= L_) l = L_ - 1;                       // clamp; result discarded
        const __hip_bfloat16* up = UO + (size_t)l * CPAD + quad * 8;
        const __hip_bfloat16* op = up + (size_t)L_ * CPAD;
        #pragma unroll
        for (int st = 0; st < 2; st++) {
            Uf[mt][st] = *(const bf16x8*)(up + st * 32);
            Of[mt][st] = *(const bf16x8*)(op + st * 32);
        }
    }

    f32x4 lsum[2] = {{0.f,0.f,0.f,0.f},{0.f,0.f,0.f,0.f}};
    f32x4 num [2] = {{0.f,0.f,0.f,0.f},{0.f,0.f,0.f,0.f}};
    const f32x4 zero = {0.f, 0.f, 0.f, 0.f};

    const __hip_bfloat16* Bp = H + ((size_t)b * WP + ni * 32 + col) * CPAD + quad * 8;

    bf16x8 Bc[2][2];
    #pragma unroll
    for (int nt = 0; nt < 2; nt++)
        #pragma unroll
        for (int st = 0; st < 2; st++)
            Bc[nt][st] = *(const bf16x8*)(Bp + (size_t)(nt * 16) * CPAD + st * 32);

    #pragma unroll 1
    for (int wt = 0; wt < WP; wt += 64) {
        const int wn = (wt + 64) & (WP - 1);     // wrap prefetch (last one discarded)
        bf16x8 Bn[2][2];
        #pragma unroll
        for (int nt = 0; nt < 2; nt++)
            #pragma unroll
            for (int st = 0; st < 2; st++)
                Bn[nt][st] = *(const bf16x8*)(Bp + (size_t)(wn + nt * 16) * CPAD + st * 32);

        #pragma unroll
        for (int nt = 0; nt < 2; nt++) {
            #pragma unroll
            for (int mt = 0; mt < 2; mt++) {
                f32x4 S = __builtin_amdgcn_mfma_f32_16x16x32_bf16(Uf[mt][0], Bc[nt][0], zero, 0, 0, 0);
                S       = __builtin_amdgcn_mfma_f32_16x16x32_bf16(Uf[mt][1], Bc[nt][1], S,    0, 0, 0);
                f32x4 T = __builtin_amdgcn_mfma_f32_16x16x32_bf16(Of[mt][0], Bc[nt][0], zero, 0, 0, 0);
                T       = __builtin_amdgcn_mfma_f32_16x16x32_bf16(Of[mt][1], Bc[nt][1], T,    0, 0, 0);
                #pragma unroll
                for (int r = 0; r < 4; r++) {
                    float p = __expf(S[r]);       // |s|<=~4: no max-subtraction needed
                    lsum[mt][r] += p;
                    num [mt][r] += p * T[r];
                }
            }
        }

        #pragma unroll
        for (int nt = 0; nt < 2; nt++)
            #pragma unroll
            for (int st = 0; st < 2; st++)
                Bc[nt][st] = Bn[nt][st];
    }

    // reduce the 16 w-cols held per (quad): xor-butterfly on lane bits 0-3
    #pragma unroll
    for (int mt = 0; mt < 2; mt++) {
        #pragma unroll
        for (int r = 0; r < 4; r++) {
            float ls = lsum[mt][r], nm = num[mt][r];
            #pragma unroll
            for (int d = 1; d < 16; d <<= 1) {
                ls += __shfl_xor(ls, d, 64);
                nm += __shfl_xor(nm, d, 64);
            }
            if (col == 0)
                red[ni][mi * 32 + mt * 16 + quad * 4 + r] = make_float2(ls, nm);
        }
    }
    __syncthreads();

    if (tid < TL) {
        int l = l0 + tid;
        if (l < L_) {
            float2 p0 = red[0][tid], p1 = red[1][tid];
            float z = (p0.y + p1.y) / (p0.x + p1.x - (float)(WP - W_LEN_)) + out_b[l];
            out[(size_t)b * L_ + l] = 1.f / (1.f + __expf(-z));
        }
    }
}

extern "C" void kernel_launch(void* const* d_in, const int* in_sizes, int n_in,
                              void* d_out, int out_size, void* d_ws, size_t ws_size,
                              hipStream_t stream) {
    const int*   x       = (const int*)  d_in[0];
    const float* W_embed = (const float*)d_in[1];
    const float* conv_w  = (const float*)d_in[2];
    const float* conv_b  = (const float*)d_in[3];
    const float* u_w     = (const float*)d_in[4];
    const float* out_w   = (const float*)d_in[5];
    const float* out_b   = (const float*)d_in[6];
    float* out = (float*)d_out;

    char* ws = (char*)d_ws;
    __hip_bfloat16* H  = (__hip_bfloat16*)ws;                       // 8*1024*64*2 = 1,048,576 B
    __hip_bfloat16* UO = (__hip_bfloat16*)(ws + 1048576);           // 2*18000*64*2 = 4,608,000 B
    float*          cwT = (float*)(ws + 1048576 + 4608000);         // 60,000 B

    {
        const int total = C_ * K_ * E_;
        transpose_kernel<<<dim3((total + 255) / 256), 256, 0, stream>>>(conv_w, cwT);
    }
    {
        const int total = 2 * L_ * CPAD;
        prep_uo<<<dim3((total + 255) / 256), 256, 0, stream>>>(u_w, out_w, UO);
    }
    {
        dim3 grid(WP / CWT, B_);
        conv_kernel<<<grid, 256, 0, stream>>>(x, W_embed, cwT, conv_b, H);
    }
    {
        dim3 grid(NLBLK, B_);
        attn_kernel<<<grid, 256, 0, stream>>>(H, UO, out_b, out);
    }
}

// Round 5
// 153.428 us; speedup vs baseline: 5.2481x; 1.1630x over previous
//
#include <hip/hip_runtime.h>
#include <hip/hip_bf16.h>
#include <cmath>

#define AS1 __attribute__((address_space(1)))
#define AS3 __attribute__((address_space(3)))

#define B_ 8
#define W_LEN_ 1000
#define WP 1024          // W padded; rows >= 1000 are exactly 0 -> lsum pad = +24, subtracted at end
#define E_ 100
#define C_ 50
#define CPAD 64          // UO k-padding (2 x K=32 MFMA steps)
#define HP 72            // H row stride in elems (144 B): conflict-free LDS B-reads, no swizzle
#define K_ 3
#define L_ 18000
#define TL 64            // labels per attn block
#define NLBLK ((L_ + TL - 1) / TL)   // 282
#define CWT 16           // w-positions per conv block
#define NSLOT (K_ * (E_ / 4))        // 75 weight slots

typedef __attribute__((ext_vector_type(8))) short bf16x8;   // 8 bf16 = 4 VGPRs
typedef __attribute__((ext_vector_type(4))) short bf16x4;   // 4 bf16 = 2 VGPRs
typedef __attribute__((ext_vector_type(4))) float f32x4;

static __device__ __forceinline__ void gl_lds16(const void* g, void* l) {
    __builtin_amdgcn_global_load_lds((const AS1 unsigned*)g, (AS3 unsigned*)l, 16, 0, 0);
}
static __device__ __forceinline__ float bf2f(short s) {
    return __uint_as_float(((unsigned)(unsigned short)s) << 16);
}

// ---------------- prep_w: conv_w (C,E,K) fp32 -> bf16x4 slots [k*25+i][c] ----------------
__global__ __launch_bounds__(256) void prep_w(
    const float* __restrict__ conv_w, bf16x4* __restrict__ cwTs)
{
    int idx = blockIdx.x * blockDim.x + threadIdx.x;
    if (idx >= NSLOT * C_) return;
    int slot = idx / C_;
    int c    = idx % C_;
    int k = slot / (E_ / 4);
    int i = slot % (E_ / 4);
    bf16x4 v;
    #pragma unroll
    for (int q = 0; q < 4; q++) {
        __hip_bfloat16 h = __float2bfloat16(conv_w[((size_t)c * E_ + 4 * i + q) * K_ + k]);
        v[q] = *reinterpret_cast<short*>(&h);
    }
    cwTs[idx] = v;
}

// ---------------- prep_uo: u_w/out_w fp32 (L,50) -> bf16 (2,L,64) zero-padded ----------------
__global__ __launch_bounds__(256) void prep_uo(
    const float* __restrict__ u_w, const float* __restrict__ out_w,
    __hip_bfloat16* __restrict__ UO)
{
    int tid = blockIdx.x * blockDim.x + threadIdx.x;
    if (tid >= 2 * L_ * CPAD) return;
    int c = tid & (CPAD - 1);
    int l = (tid >> 6) % L_;
    int m = tid / (L_ * CPAD);
    const float* src = m ? out_w : u_w;
    float v = (c < C_) ? src[(size_t)l * C_ + c] : 0.f;
    UO[tid] = __float2bfloat16(v);
}

// ---------------- conv: LDS weights (bf16) + LDS embed rows -> bf16 H (B,WP,HP) ----------------
// Block 256 = (c 0..63) x (wq 0..3); thread computes 4 w, weights ds_read_b64 conflict-free.
__global__ __launch_bounds__(256) void conv_kernel(
    const int* __restrict__ x,          // (B, W)
    const float* __restrict__ W_embed,  // (V, E)
    const bf16x4* __restrict__ cwTs,    // (NSLOT, C)
    const float* __restrict__ conv_b,   // (C,)
    __hip_bfloat16* __restrict__ H)     // (B, WP, HP)
{
    __shared__ float4 emb_s[(CWT + 2) * (E_ / 4)];   // 18 rows x 25 f4 = 7.2 KB
    __shared__ bf16x4 wS[NSLOT * C_];                // 75 x 50 x 8B = 30 KB

    const int b  = blockIdx.y;
    const int w0 = blockIdx.x * CWT;
    const int tid = threadIdx.x;

    for (int i = tid; i < NSLOT * C_; i += 256) wS[i] = cwTs[i];

    for (int i = tid; i < (CWT + 2) * (E_ / 4); i += 256) {
        int row = i / (E_ / 4);
        int e4  = i % (E_ / 4);
        int ws  = w0 - 1 + row;
        float4 v = make_float4(0.f, 0.f, 0.f, 0.f);
        if ((unsigned)ws < (unsigned)W_LEN_)
            v = ((const float4*)(W_embed + (size_t)x[b * W_LEN_ + ws] * E_))[e4];
        emb_s[i] = v;
    }
    __syncthreads();

    const int c  = tid & 63;
    const int wq = tid >> 6;          // 0..3
    const int cc = (c < C_) ? c : 0;  // dead lanes compute c=0, write 0

    f32x4 acc[4];
    const float bias = conv_b[cc];
    #pragma unroll
    for (int j = 0; j < 4; j++) acc[j] = (f32x4){bias, 0.f, 0.f, 0.f};

    const float4* eb = &emb_s[wq * 4 * (E_ / 4)];

    #pragma unroll 5
    for (int i = 0; i < E_ / 4; i++) {
        bf16x4 kb0 = wS[i * C_ + cc];
        bf16x4 kb1 = wS[(25 + i) * C_ + cc];
        bf16x4 kb2 = wS[(50 + i) * C_ + cc];
        float4 k0 = make_float4(bf2f(kb0[0]), bf2f(kb0[1]), bf2f(kb0[2]), bf2f(kb0[3]));
        float4 k1 = make_float4(bf2f(kb1[0]), bf2f(kb1[1]), bf2f(kb1[2]), bf2f(kb1[3]));
        float4 k2 = make_float4(bf2f(kb2[0]), bf2f(kb2[1]), bf2f(kb2[2]), bf2f(kb2[3]));
        float4 e0 = eb[i],       e1 = eb[25 + i],  e2 = eb[50 + i];
        float4 e3 = eb[75 + i],  e4 = eb[100 + i], e5 = eb[125 + i];
        acc[0].x += e0.x*k0.x + e1.x*k1.x + e2.x*k2.x;
        acc[0].y += e0.y*k0.y + e1.y*k1.y + e2.y*k2.y;
        acc[0].z += e0.z*k0.z + e1.z*k1.z + e2.z*k2.z;
        acc[0].w += e0.w*k0.w + e1.w*k1.w + e2.w*k2.w;
        acc[1].x += e1.x*k0.x + e2.x*k1.x + e3.x*k2.x;
        acc[1].y += e1.y*k0.y + e2.y*k1.y + e3.y*k2.y;
        acc[1].z += e1.z*k0.z + e2.z*k1.z + e3.z*k2.z;
        acc[1].w += e1.w*k0.w + e2.w*k1.w + e3.w*k2.w;
        acc[2].x += e2.x*k0.x + e3.x*k1.x + e4.x*k2.x;
        acc[2].y += e2.y*k0.y + e3.y*k1.y + e4.y*k2.y;
        acc[2].z += e2.z*k0.z + e3.z*k1.z + e4.z*k2.z;
        acc[2].w += e2.w*k0.w + e3.w*k1.w + e4.w*k2.w;
        acc[3].x += e3.x*k0.x + e4.x*k1.x + e5.x*k2.x;
        acc[3].y += e3.y*k0.y + e4.y*k1.y + e5.y*k2.y;
        acc[3].z += e3.z*k0.z + e4.z*k1.z + e5.z*k2.z;
        acc[3].w += e3.w*k0.w + e4.w*k1.w + e5.w*k2.w;
    }

    #pragma unroll
    for (int j = 0; j < 4; j++) {
        int w = w0 + wq * 4 + j;
        float v = 0.f;
        if (c < C_ && w < W_LEN_)
            v = tanhf((acc[j].x + acc[j].z) + (acc[j].y + acc[j].w));
        __hip_bfloat16* row = H + ((size_t)b * WP + w) * HP;
        row[c] = __float2bfloat16(v);
        if (c < HP - 64) row[64 + c] = __float2bfloat16(0.f);   // zero-fill cols 64..71
    }
}

// ---------------- attn: LDS-staged dual-GEMM + fused softmax-pool ----------------
// Grid (NLBLK, B). 4 waves: (mi,ni); wave tile 32 lbl x 32 w. H tile (64w x 72c bf16 = 9216B)
// double-buffered in LDS via global_load_lds(16B); B-frags via ds_read_b128 (2-way = free).
__global__ __launch_bounds__(256) void attn_kernel(
    const __hip_bfloat16* __restrict__ H,   // (B, WP, HP)
    const __hip_bfloat16* __restrict__ UO,  // (2, L, CPAD)
    const float* __restrict__ out_b,        // (L,)
    float* __restrict__ out)                // (B, L)
{
    __shared__ __hip_bfloat16 Hs[2][64 * HP];   // 2 x 9216 B
    __shared__ float2 red[2][TL];

    const int b  = blockIdx.y;
    const int l0 = blockIdx.x * TL;
    const int tid  = threadIdx.x;
    const int lane = tid & 63;
    const int wid  = tid >> 6;
    const int mi = wid & 1, ni = wid >> 1;
    const int col = lane & 15, quad = lane >> 4;

    // loop-invariant A-fragments for U and O
    bf16x8 Uf[2][2], Of[2][2];
    #pragma unroll
    for (int mt = 0; mt < 2; mt++) {
        int l = l0 + mi * 32 + mt * 16 + col;
        if (l >= L_) l = L_ - 1;                       // clamp; result discarded
        const __hip_bfloat16* up = UO + (size_t)l * CPAD + quad * 8;
        const __hip_bfloat16* op = up + (size_t)L_ * CPAD;
        #pragma unroll
        for (int st = 0; st < 2; st++) {
            Uf[mt][st] = *(const bf16x8*)(up + st * 32);
            Of[mt][st] = *(const bf16x8*)(op + st * 32);
        }
    }

    f32x4 lsum[2] = {{0.f,0.f,0.f,0.f},{0.f,0.f,0.f,0.f}};
    f32x4 num [2] = {{0.f,0.f,0.f,0.f},{0.f,0.f,0.f,0.f}};
    const f32x4 zero = {0.f, 0.f, 0.f, 0.f};

    const __hip_bfloat16* Hb = H + (size_t)b * WP * HP;

    // stage tile 0: 9216 B = 576 x 16B chunks; threads do chunks tid, tid+256, (tid+512 if wave 0)
    {
        const char* g = (const char*)Hb;
        char* l = (char*)&Hs[0][0];
        gl_lds16(g + tid * 16,         l + tid * 16);
        gl_lds16(g + (tid + 256) * 16, l + (tid + 256) * 16);
        if (tid < 64)
            gl_lds16(g + (tid + 512) * 16, l + (tid + 512) * 16);
    }

    #pragma unroll 1
    for (int wt = 0; wt < WP; wt += 64) {
        const int cur = (wt >> 6) & 1;
        __syncthreads();   // drains own global_load_lds (vmcnt) + all waves done with buf cur^1

        if (wt + 64 < WP) {
            const char* g = (const char*)(Hb + (size_t)(wt + 64) * HP);
            char* l = (char*)&Hs[cur ^ 1][0];
            gl_lds16(g + tid * 16,         l + tid * 16);
            gl_lds16(g + (tid + 256) * 16, l + (tid + 256) * 16);
            if (tid < 64)
                gl_lds16(g + (tid + 512) * 16, l + (tid + 512) * 16);
        }

        // B-frags from LDS: row = ni*32 + nt*16 + col, k-bytes quad*16 + st*64 in 144B row
        bf16x8 Bc[2][2];
        #pragma unroll
        for (int nt = 0; nt < 2; nt++)
            #pragma unroll
            for (int st = 0; st < 2; st++)
                Bc[nt][st] = *(const bf16x8*)(&Hs[cur][(ni * 32 + nt * 16 + col) * HP
                                                       + quad * 8 + st * 32]);

        #pragma unroll
        for (int nt = 0; nt < 2; nt++) {
            #pragma unroll
            for (int mt = 0; mt < 2; mt++) {
                f32x4 S = __builtin_amdgcn_mfma_f32_16x16x32_bf16(Uf[mt][0], Bc[nt][0], zero, 0, 0, 0);
                S       = __builtin_amdgcn_mfma_f32_16x16x32_bf16(Uf[mt][1], Bc[nt][1], S,    0, 0, 0);
                f32x4 T = __builtin_amdgcn_mfma_f32_16x16x32_bf16(Of[mt][0], Bc[nt][0], zero, 0, 0, 0);
                T       = __builtin_amdgcn_mfma_f32_16x16x32_bf16(Of[mt][1], Bc[nt][1], T,    0, 0, 0);
                #pragma unroll
                for (int r = 0; r < 4; r++) {
                    float p = __expf(S[r]);       // |s|<=~4: no max-subtraction needed
                    lsum[mt][r] += p;
                    num [mt][r] += p * T[r];
                }
            }
        }
    }

    // reduce the 16 w-cols held per (quad): xor-butterfly on lane bits 0-3
    #pragma unroll
    for (int mt = 0; mt < 2; mt++) {
        #pragma unroll
        for (int r = 0; r < 4; r++) {
            float ls = lsum[mt][r], nm = num[mt][r];
            #pragma unroll
            for (int d = 1; d < 16; d <<= 1) {
                ls += __shfl_xor(ls, d, 64);
                nm += __shfl_xor(nm, d, 64);
            }
            if (col == 0)
                red[ni][mi * 32 + mt * 16 + quad * 4 + r] = make_float2(ls, nm);
        }
    }
    __syncthreads();

    if (tid < TL) {
        int l = l0 + tid;
        if (l < L_) {
            float2 p0 = red[0][tid], p1 = red[1][tid];
            float z = (p0.y + p1.y) / (p0.x + p1.x - (float)(WP - W_LEN_)) + out_b[l];
            out[(size_t)b * L_ + l] = 1.f / (1.f + __expf(-z));
        }
    }
}

extern "C" void kernel_launch(void* const* d_in, const int* in_sizes, int n_in,
                              void* d_out, int out_size, void* d_ws, size_t ws_size,
                              hipStream_t stream) {
    const int*   x       = (const int*)  d_in[0];
    const float* W_embed = (const float*)d_in[1];
    const float* conv_w  = (const float*)d_in[2];
    const float* conv_b  = (const float*)d_in[3];
    const float* u_w     = (const float*)d_in[4];
    const float* out_w   = (const float*)d_in[5];
    const float* out_b   = (const float*)d_in[6];
    float* out = (float*)d_out;

    char* ws = (char*)d_ws;
    __hip_bfloat16* H  = (__hip_bfloat16*)ws;                 // 8*1024*72*2 = 1,179,648 B
    __hip_bfloat16* UO = (__hip_bfloat16*)(ws + 1179648);     // 2*18000*64*2 = 4,608,000 B
    bf16x4*       cwTs = (bf16x4*)(ws + 1179648 + 4608000);   // 75*50*8 = 30,000 B

    {
        const int total = NSLOT * C_;
        prep_w<<<dim3((total + 255) / 256), 256, 0, stream>>>(conv_w, cwTs);
    }
    {
        const int total = 2 * L_ * CPAD;
        prep_uo<<<dim3((total + 255) / 256), 256, 0, stream>>>(u_w, out_w, UO);
    }
    {
        dim3 grid(WP / CWT, B_);
        conv_kernel<<<grid, 256, 0, stream>>>(x, W_embed, cwTs, conv_b, H);
    }
    {
        dim3 grid(NLBLK, B_);
        attn_kernel<<<grid, 256, 0, stream>>>(H, UO, out_b, out);
    }
}